// Round 6
// baseline (1446.493 us; speedup 1.0000x reference)
//
#include <hip/hip_runtime.h>
#include <stdint.h>
#include <stddef.h>

// ---------- types ----------
typedef __bf16 bf16_8 __attribute__((ext_vector_type(8)));
typedef float  f32x4  __attribute__((ext_vector_type(4)));

__device__ __forceinline__ unsigned short f2bf(float f) {
    unsigned u = __float_as_uint(f);
    unsigned r = (u + 0x7fffu + ((u >> 16) & 1u)) >> 16;   // RTN-even
    return (unsigned short)r;
}
__device__ __forceinline__ float bf2f(unsigned short s) {
    return __uint_as_float(((unsigned)s) << 16);
}
__device__ __forceinline__ void split3(float v, unsigned short& h, unsigned short& l, unsigned short& l2) {
    h = f2bf(v);
    float r1 = v - bf2f(h);
    l = f2bf(r1);
    l2 = f2bf(r1 - bf2f(l));
}
__device__ __forceinline__ void split2(float v, unsigned short& h, unsigned short& l) {
    h = f2bf(v);
    l = f2bf(v - bf2f(h));
}

// ---------- weight transpose+split: src [K][N] f32 -> dst planes [P][N][K] bf16 ----------
template<int P>
__global__ __launch_bounds__(256)
void wsplit_kernel(const float* __restrict__ s0, const float* __restrict__ s1,
                   const float* __restrict__ s2, const float* __restrict__ s3,
                   unsigned short* __restrict__ d0, unsigned short* __restrict__ d1,
                   unsigned short* __restrict__ d2, unsigned short* __restrict__ d3,
                   int K, int N, int nper, size_t sstride, size_t dstride)
{
    const int z = blockIdx.z;
    const int arr = z / nper, e = z - arr * nper;
    const float* src = (arr == 0 ? s0 : arr == 1 ? s1 : arr == 2 ? s2 : s3) + (size_t)e * sstride;
    unsigned short* dst = (arr == 0 ? d0 : arr == 1 ? d1 : arr == 2 ? d2 : d3) + (size_t)e * dstride;
    const size_t NK = (size_t)N * K;
    __shared__ float T[64][65];
    const int n0 = blockIdx.x * 64, k0 = blockIdx.y * 64;
    const int tid = threadIdx.x;
#pragma unroll
    for (int i = 0; i < 16; ++i) {
        int idx = tid + (i << 8);
        int kk = idx >> 6, nn = idx & 63;
        T[kk][nn] = src[(size_t)(k0 + kk) * N + n0 + nn];
    }
    __syncthreads();
#pragma unroll
    for (int i = 0; i < 4; ++i) {
        int idx = (tid + (i << 8)) << 2;
        int nn = idx >> 6, kk = idx & 63;
        ushort4 hv, lv, l2v;
        unsigned short* hp = (unsigned short*)&hv;
        unsigned short* lp = (unsigned short*)&lv;
        unsigned short* l2p = (unsigned short*)&l2v;
#pragma unroll
        for (int j = 0; j < 4; ++j) {
            float v = T[kk + j][nn];
            unsigned short h = f2bf(v);
            hp[j] = h;
            if (P == 3) {
                float r1 = v - bf2f(h);
                unsigned short l = f2bf(r1);
                lp[j] = l;
                l2p[j] = f2bf(r1 - bf2f(l));
            }
        }
        unsigned short* dp = dst + (size_t)(n0 + nn) * K + k0 + kk;
        *(ushort4*)dp = hv;
        if (P == 3) {
            *(ushort4*)(dp + NK) = lv;
            *(ushort4*)(dp + 2 * NK) = l2v;
        }
    }
}

// ---------- GEMM: C = A * B via bf16 MFMA, 128x128 tile, BK=32, expert-batched in z ----------
// TERMS=6: 3-term split both sides (fp32-grade). TERMS=1: plain bf16.
// AMODE: 0 direct (+e*astride); 1 compact base+row; 2 gather flat[base+row].
// CMODE: 0 direct (+e*cstride); 1 compact masked; 2 scatter flat[base+row] masked.
// BPRE: 0 = B f32 [K][N], in-loop split+transpose; 1 = B pre-split bf16 planes [P][N][K].
// A16:  0 = A f32, in-loop split; 1 = A bf16 planes [NPL][M][K] (plane stride = astride).
// C16:  0 = C f32; 1 = C bf16; 2 = C 3-plane bf16 split (plane stride = cstride, no e-offset);
//       3 = C 2-plane bf16 split (plane stride = cstride, no e-offset).
template<int TERMS, int AMODE, int CMODE, int NW, int BPRE, int A16, int C16>
__global__ __launch_bounds__(256, 2)
void gemm_kernel(const void* __restrict__ Av,
                 const void* __restrict__ B0, const void* __restrict__ B1, const void* __restrict__ B2,
                 void* __restrict__ C0, void* __restrict__ C1, void* __restrict__ C2,
                 int M, int N, int K,
                 size_t astride, size_t bstride, size_t cstride,
                 const int* __restrict__ OFF, const int* __restrict__ flat)
{
    const int z = blockIdx.z;
    const int e = z / NW, w = z - e * NW;
    int base = 0, cnt = M;
    if (AMODE == 1 || AMODE == 2 || CMODE == 1 || CMODE == 2) {
        base = OFF[e * 8];
        cnt  = OFF[e * 8 + 8] - base;
        if ((int)blockIdx.x * 128 >= cnt) return;
    }
    const void* Bsel = (NW == 3 ? (w == 0 ? B0 : w == 1 ? B1 : B2) : B0);
    void*       Csel = (NW == 3 ? (w == 0 ? C0 : w == 1 ? C1 : C2) : C0);
    const float*          Af = (const float*)Av + (size_t)e * astride;
    const unsigned short* As = (const unsigned short*)Av;
    const float*          Bf = (const float*)Bsel + (size_t)e * bstride;
    const unsigned short* Bp = (const unsigned short*)Bsel + (size_t)e * bstride;
    float*          Cf = (float*)Csel + (size_t)e * cstride;
    unsigned short* Cs = (unsigned short*)Csel + (size_t)e * cstride;
    unsigned short* Cp = (unsigned short*)Csel;          // C16>=2: cstride is plane stride
    const size_t NKb = (size_t)N * K;

    constexpr int NPL = (TERMS == 6) ? 3 : 1;
    __shared__ unsigned short Asm[NPL][128 * 40];   // padded stride 40
    __shared__ unsigned short Bsm[NPL][128 * 40];   // Bsm[n][k]

    const int tid   = threadIdx.x;
    const int lane  = tid & 63;
    const int wid   = tid >> 6;
    const int wm    = wid & 1, wn = wid >> 1;
    const int mlane = lane & 15, quad = lane >> 4;
    const int row0  = blockIdx.x * 128;
    const int col0  = blockIdx.y * 128;

    f32x4 acc[4][4];
#pragma unroll
    for (int i = 0; i < 4; ++i)
#pragma unroll
        for (int j = 0; j < 4; ++j)
#pragma unroll
            for (int r = 0; r < 4; ++r) acc[i][j][r] = 0.f;

    for (int k0 = 0; k0 < K; k0 += 32) {
        // ---- stage A ----
        if (A16 == 0) {
#pragma unroll
            for (int i = 0; i < 4; ++i) {
                int idx = tid + (i << 8);
                int r = idx >> 3;
                int c = (idx & 7) << 2;
                int lr = row0 + r;
                if (AMODE != 0) lr = min(lr, cnt - 1);
                size_t arow = (AMODE == 2) ? (size_t)flat[base + lr]
                            : (AMODE == 1) ? (size_t)(base + lr) : (size_t)lr;
                const float4 a = *(const float4*)(Af + arow * K + k0 + c);
                float av[4] = {a.x, a.y, a.z, a.w};
                ushort4 hv, lv, l2v;
                unsigned short* hp  = (unsigned short*)&hv;
                unsigned short* lp  = (unsigned short*)&lv;
                unsigned short* l2p = (unsigned short*)&l2v;
#pragma unroll
                for (int j = 0; j < 4; ++j) {
                    unsigned short h = f2bf(av[j]);
                    hp[j] = h;
                    if (TERMS == 6) {
                        float r1 = av[j] - bf2f(h);
                        unsigned short l = f2bf(r1);
                        lp[j]  = l;
                        l2p[j] = f2bf(r1 - bf2f(l));
                    }
                }
                *(ushort4*)&Asm[0][r * 40 + c] = hv;
                if (TERMS == 6) {
                    *(ushort4*)&Asm[1][r * 40 + c] = lv;
                    *(ushort4*)&Asm[2][r * 40 + c] = l2v;
                }
            }
        } else {
#pragma unroll
            for (int p = 0; p < NPL; ++p)
#pragma unroll
                for (int j = 0; j < 2; ++j) {
                    int c = tid * 2 + j;                 // 512 chunks of 8 shorts
                    int r = c >> 2, q8 = (c & 3) << 3;
                    int lr = row0 + r;
                    if (AMODE != 0) lr = min(lr, cnt - 1);
                    size_t arow = (AMODE == 2) ? (size_t)flat[base + lr]
                                : (AMODE == 1) ? (size_t)(base + lr) : (size_t)lr;
                    *(uint4*)&Asm[p][r * 40 + q8] =
                        *(const uint4*)(As + (size_t)p * astride + arow * K + k0 + q8);
                }
        }
        // ---- stage B ----
        if (BPRE == 0) {
#pragma unroll
            for (int i = 0; i < 2; ++i) {
                int idx = tid + (i << 8);
                int kk = idx >> 4;
                int n8 = (idx & 15) << 3;
                const float* bp = Bf + (size_t)(k0 + kk) * N + col0 + n8;
                const float4 b0 = *(const float4*)bp;
                const float4 b1 = *(const float4*)(bp + 4);
                float bv[8] = {b0.x, b0.y, b0.z, b0.w, b1.x, b1.y, b1.z, b1.w};
#pragma unroll
                for (int j = 0; j < 8; ++j) {
                    unsigned short h = f2bf(bv[j]);
                    Bsm[0][(n8 + j) * 40 + kk] = h;
                    if (TERMS == 6) {
                        float r1 = bv[j] - bf2f(h);
                        unsigned short l = f2bf(r1);
                        Bsm[1][(n8 + j) * 40 + kk] = l;
                        Bsm[2][(n8 + j) * 40 + kk] = f2bf(r1 - bf2f(l));
                    }
                }
            }
        } else {
#pragma unroll
            for (int p = 0; p < NPL; ++p)
#pragma unroll
                for (int j = 0; j < 2; ++j) {
                    int c = tid * 2 + j;
                    int r = c >> 2, q8 = (c & 3) << 3;
                    *(uint4*)&Bsm[p][r * 40 + q8] =
                        *(const uint4*)(Bp + (size_t)p * NKb + (size_t)(col0 + r) * K + k0 + q8);
                }
        }
        __syncthreads();

        bf16_8 fa[3][4], fb[3][4];
#pragma unroll
        for (int t = 0; t < 4; ++t) {
            int ar = (wm * 64 + t * 16 + mlane) * 40 + quad * 8;
            int br = (wn * 64 + t * 16 + mlane) * 40 + quad * 8;
            fa[0][t] = *(const bf16_8*)&Asm[0][ar];
            fb[0][t] = *(const bf16_8*)&Bsm[0][br];
            if (TERMS == 6) {
                fa[1][t] = *(const bf16_8*)&Asm[1][ar];
                fa[2][t] = *(const bf16_8*)&Asm[2][ar];
                fb[1][t] = *(const bf16_8*)&Bsm[1][br];
                fb[2][t] = *(const bf16_8*)&Bsm[2][br];
            }
        }
        const int ta[6] = {0, 0, 1, 0, 1, 2};
        const int tb[6] = {0, 1, 0, 2, 1, 0};
#pragma unroll
        for (int s = 0; s < TERMS; ++s)
#pragma unroll
            for (int mt = 0; mt < 4; ++mt)
#pragma unroll
                for (int nt = 0; nt < 4; ++nt)
                    acc[mt][nt] = __builtin_amdgcn_mfma_f32_16x16x32_bf16(
                        fa[ta[s]][mt], fb[tb[s]][nt], acc[mt][nt], 0, 0, 0);
        __syncthreads();
    }

    // ---- epilogue: C/D layout col=lane&15, row=quad*4+reg ----
#pragma unroll
    for (int mt = 0; mt < 4; ++mt)
#pragma unroll
        for (int nt = 0; nt < 4; ++nt) {
            int c = col0 + wn * 64 + nt * 16 + mlane;
#pragma unroll
            for (int j = 0; j < 4; ++j) {
                int lr = row0 + wm * 64 + mt * 16 + quad * 4 + j;
                if ((CMODE == 1 || CMODE == 2) && lr >= cnt) continue;
                size_t crow = (CMODE == 2) ? (size_t)flat[base + lr]
                            : (CMODE == 1) ? (size_t)(base + lr) : (size_t)lr;
                size_t o = crow * N + c;
                if (C16 == 2) {
                    unsigned short h, l, l2;
                    split3(acc[mt][nt][j], h, l, l2);
                    Cp[o] = h; Cp[cstride + o] = l; Cp[2 * cstride + o] = l2;
                } else if (C16 == 3) {
                    unsigned short h, l;
                    split2(acc[mt][nt][j], h, l);
                    Cp[o] = h; Cp[cstride + o] = l;
                } else if (C16 == 1) {
                    Cs[o] = f2bf(acc[mt][nt][j]);
                } else {
                    Cf[o] = acc[mt][nt][j];
                }
            }
        }
}

// ---------- meanV FFN chain: out[e][b][n] (+)= sum_k in[e][b][k]*W[e][k][n], b<8 ----------
__global__ __launch_bounds__(256)
void meanv_gemm_kernel(const float* __restrict__ in, const float* __restrict__ W,
                       float* __restrict__ out, int N, int K,
                       size_t instride, size_t wstride, size_t outstride)
{
    const int e  = blockIdx.z;
    const int nl = threadIdx.x & 63;
    const int kg = threadIdx.x >> 6;
    const int n  = blockIdx.x * 64 + nl;
    const int k0 = blockIdx.y * 512;

    const float* inp = in + (size_t)e * instride + k0;
    const float* wp  = W + (size_t)e * wstride + (size_t)(k0 + kg * 128) * N + n;

    __shared__ float mv[8][512];
    for (int i = threadIdx.x; i < 4096; i += 256) {
        int b = i >> 9, k = i & 511;
        mv[b][k] = inp[(size_t)b * K + k];
    }
    __syncthreads();

    float acc[8] = {0.f, 0.f, 0.f, 0.f, 0.f, 0.f, 0.f, 0.f};
#pragma unroll 8
    for (int k = 0; k < 128; ++k) {
        float wv = wp[(size_t)k * N];
        const float* mk = &mv[0][kg * 128 + k];
#pragma unroll
        for (int b = 0; b < 8; ++b) acc[b] += mk[b * 512] * wv;
    }

    __shared__ float red[4][8][64];
#pragma unroll
    for (int b = 0; b < 8; ++b) red[kg][b][nl] = acc[b];
    __syncthreads();
    if (kg == 0) {
        float* op = out + (size_t)e * outstride + n;
#pragma unroll
        for (int b = 0; b < 8; ++b) {
            float s = red[0][b][nl] + red[1][b][nl] + red[2][b][nl] + red[3][b][nl];
            if (gridDim.y == 1) op[(size_t)b * N] = s;
            else                atomicAdd(&op[(size_t)b * N], s);
        }
    }
}

// ---------- MFMA split-bf16 flash attention (shared block), fp32-grade ----------
// K/V arrive PRE-SPLIT as 3 bf16 planes (QKV GEMM epilogue, C16=2);
// per-tile staging is pure copies. Bit-identical math vs in-loop split.
// Kp plane stride 4194304 shorts; Vp plane stride 16777216 shorts.
__global__ __launch_bounds__(256, 2)
void attn_kernel(const float* __restrict__ Q, const unsigned short* __restrict__ Kp,
                 const unsigned short* __restrict__ Vp, float* __restrict__ O)
{
    __shared__ __align__(16) unsigned short Ks[3][2][32][40];  // [plane][dchunk][key][dmod32+pad]
    __shared__ __align__(16) unsigned short Vt[3][64][40];     // [plane][d][key+pad]
    __shared__ __align__(16) unsigned short U[15360];          // Qs [3][2][64][40] / P [4][3][16][40]

    const int tid = threadIdx.x;
    const int lane = tid & 63;
    const int w = tid >> 6;
    const int mlane = lane & 15, quad = lane >> 4;

    const int qt = blockIdx.x & 15;
    const int h  = (blockIdx.x >> 4) & 7;
    const int b  = blockIdx.x >> 7;
    const size_t rowbase = (size_t)b * 1024;
    const int colbase = h * 64;

    // ---- stage Q tile (64 q x 64 d) as 3 bf16 planes (once per block) ----
#pragma unroll
    for (int i = 0; i < 4; ++i) {
        int idx = tid + (i << 8);
        int r = idx >> 4, c4 = (idx & 15) << 2;
        const float4 a = *(const float4*)(Q + (rowbase + qt * 64 + r) * 512 + colbase + c4);
        float av[4] = {a.x, a.y, a.z, a.w};
        ushort4 hv, lv, l2v;
        unsigned short* hp  = (unsigned short*)&hv;
        unsigned short* lp  = (unsigned short*)&lv;
        unsigned short* l2p = (unsigned short*)&l2v;
#pragma unroll
        for (int j = 0; j < 4; ++j) split3(av[j], hp[j], lp[j], l2p[j]);
        int ch = c4 >> 5, cm = c4 & 31;
        *(ushort4*)&U[(((0 * 2 + ch) * 64) + r) * 40 + cm] = hv;
        *(ushort4*)&U[(((1 * 2 + ch) * 64) + r) * 40 + cm] = lv;
        *(ushort4*)&U[(((2 * 2 + ch) * 64) + r) * 40 + cm] = l2v;
    }
    __syncthreads();

    // Q B-fragments: col=q=w*16+mlane, k=d=c*32+quad*8+j  (persist in regs)
    bf16_8 fq[3][2];
#pragma unroll
    for (int p = 0; p < 3; ++p)
#pragma unroll
        for (int c = 0; c < 2; ++c)
            fq[p][c] = *(const bf16_8*)&U[(((p * 2 + c) * 64) + (w * 16 + mlane)) * 40 + quad * 8];
    __syncthreads();   // all waves done reading Qs before P region reuses U

    f32x4 oacc[4];     // O^T frags: d = mm*16+quad*4+j, q = mlane
#pragma unroll
    for (int i = 0; i < 4; ++i)
#pragma unroll
        for (int j = 0; j < 4; ++j) oacc[i][j] = 0.f;
    float m_run = -1e30f, l_run = 0.f;

    const int ta[6] = {0, 0, 1, 0, 1, 2};
    const int tb[6] = {0, 1, 0, 2, 1, 0};

    // K staging indices (constant across tiles): 256 thr x 8 shorts = 32 keys x 64 d
    const int kr = tid >> 3, kc8 = (tid & 7) << 3;
    const int kch = kc8 >> 5, kcm = kc8 & 31;

    for (int tt = 0; tt < 32; ++tt) {
        __syncthreads();
        // ---- stage K tile: pure uint4 copies from 3 planes ----
        {
            const size_t g = (rowbase + tt * 32 + kr) * 512 + colbase + kc8;
#pragma unroll
            for (int p = 0; p < 3; ++p)
                *(uint4*)&Ks[p][kch][kr][kcm] = *(const uint4*)(Kp + (size_t)p * 4194304 + g);
        }
        // ---- stage V tile transposed: 2 passes x 256 thr -> 64 d x 32 keys ----
#pragma unroll
        for (int i = 0; i < 2; ++i) {
            int idx = tid + (i << 8);
            int vd = idx & 63, vk4 = (idx >> 6) << 2;
            const size_t g = (rowbase + tt * 32 + vk4) * 512 + colbase + vd;
#pragma unroll
            for (int p = 0; p < 3; ++p) {
                const unsigned short* vp = Vp + (size_t)p * 16777216 + g;
                ushort4 vv;
                vv.x = vp[0]; vv.y = vp[512]; vv.z = vp[1024]; vv.w = vp[1536];
                *(ushort4*)&Vt[p][vd][vk4] = vv;
            }
        }
        __syncthreads();

        // ---- S^T = K·Q^T, 6-term ----
        f32x4 sacc[2];
#pragma unroll
        for (int mm = 0; mm < 2; ++mm)
#pragma unroll
            for (int j = 0; j < 4; ++j) sacc[mm][j] = 0.f;
        bf16_8 fk[3][2][2];
#pragma unroll
        for (int p = 0; p < 3; ++p)
#pragma unroll
            for (int c = 0; c < 2; ++c)
#pragma unroll
                for (int mm = 0; mm < 2; ++mm)
                    fk[p][c][mm] = *(const bf16_8*)&Ks[p][c][mm * 16 + mlane][quad * 8];
#pragma unroll
        for (int s = 0; s < 6; ++s)
#pragma unroll
            for (int c = 0; c < 2; ++c)
#pragma unroll
                for (int mm = 0; mm < 2; ++mm)
                    sacc[mm] = __builtin_amdgcn_mfma_f32_16x16x32_bf16(
                        fk[ta[s]][c][mm], fq[tb[s]][c], sacc[mm], 0, 0, 0);

        // ---- online softmax: lane owns q=mlane, keys mm*16+quad*4+j ----
        float sv[2][4];
#pragma unroll
        for (int mm = 0; mm < 2; ++mm)
#pragma unroll
            for (int j = 0; j < 4; ++j) sv[mm][j] = sacc[mm][j] * 0.125f;
        float tmax = sv[0][0];
#pragma unroll
        for (int mm = 0; mm < 2; ++mm)
#pragma unroll
            for (int j = 0; j < 4; ++j) tmax = fmaxf(tmax, sv[mm][j]);
        tmax = fmaxf(tmax, __shfl_xor(tmax, 16));
        tmax = fmaxf(tmax, __shfl_xor(tmax, 32));
        float mnew = fmaxf(m_run, tmax);
        float alpha = __expf(m_run - mnew);
        float lsum = 0.f;
#pragma unroll
        for (int mm = 0; mm < 2; ++mm)
#pragma unroll
            for (int j = 0; j < 4; ++j) {
                float p = __expf(sv[mm][j] - mnew);
                sv[mm][j] = p;
                lsum += p;
            }
        lsum += __shfl_xor(lsum, 16);
        lsum += __shfl_xor(lsum, 32);
        l_run = l_run * alpha + lsum;
        m_run = mnew;
#pragma unroll
        for (int mm = 0; mm < 4; ++mm)
#pragma unroll
            for (int j = 0; j < 4; ++j) oacc[mm][j] *= alpha;

        // ---- split P to 3 bf16 planes, per-wave LDS round-trip ----
#pragma unroll
        for (int mm = 0; mm < 2; ++mm) {
            ushort4 hv, lv, l2v;
            unsigned short* hp  = (unsigned short*)&hv;
            unsigned short* lp  = (unsigned short*)&lv;
            unsigned short* l2p = (unsigned short*)&l2v;
#pragma unroll
            for (int j = 0; j < 4; ++j) split3(sv[mm][j], hp[j], lp[j], l2p[j]);
            int col = mm * 16 + quad * 4;
            *(ushort4*)&U[((w * 3 + 0) * 16 + mlane) * 40 + col] = hv;
            *(ushort4*)&U[((w * 3 + 1) * 16 + mlane) * 40 + col] = lv;
            *(ushort4*)&U[((w * 3 + 2) * 16 + mlane) * 40 + col] = l2v;
        }

        // ---- O^T += V^T·P^T, 6-term ----
        bf16_8 fp[3], fv[3][4];
#pragma unroll
        for (int p = 0; p < 3; ++p) {
            fp[p] = *(const bf16_8*)&U[((w * 3 + p) * 16 + mlane) * 40 + quad * 8];
#pragma unroll
            for (int mm = 0; mm < 4; ++mm)
                fv[p][mm] = *(const bf16_8*)&Vt[p][mm * 16 + mlane][quad * 8];
        }
#pragma unroll
        for (int s = 0; s < 6; ++s)
#pragma unroll
            for (int mm = 0; mm < 4; ++mm)
                oacc[mm] = __builtin_amdgcn_mfma_f32_16x16x32_bf16(
                    fv[ta[s]][mm], fp[tb[s]], oacc[mm], 0, 0, 0);
    }

    // ---- epilogue: lane holds q=mlane, d=mm*16+quad*4+j ----
    const float inv = 1.f / l_run;
    const size_t orow = (rowbase + qt * 64 + w * 16 + mlane) * 512 + colbase;
#pragma unroll
    for (int mm = 0; mm < 4; ++mm)
#pragma unroll
        for (int j = 0; j < 4; ++j)
            O[orow + mm * 16 + quad * 4 + j] = oacc[mm][j] * inv;
}

// ---------- MFMA split-bf16 compacted expert attention (3-term, 2-plane) ----------
// K/V arrive pre-split as 2 bf16 planes (expert QKV GEMM, C16=3; plane stride
// 4194304 shorts). Per-tile staging is pure copies. Bit-identical split values.
__global__ __launch_bounds__(256, 3)
void attn_compact_kernel(const float* __restrict__ Qc, const unsigned short* __restrict__ Kc,
                         const unsigned short* __restrict__ Vc, const float* __restrict__ meanV,
                         unsigned short* __restrict__ AOc, const int* __restrict__ OFF)
{
    const int qt = blockIdx.x & 15;
    const int h  = (blockIdx.x >> 4) & 7;
    const int e  = (blockIdx.x >> 7) & 3;
    const int b  = blockIdx.x >> 9;
    const int base = OFF[e * 8 + b];
    const int c    = OFF[e * 8 + b + 1] - base;
    if (qt * 64 >= c) return;
    const int nq = min(64, c - qt * 64);

    __shared__ __align__(16) unsigned short Ks[2][2][32][40];  // [plane][dchunk][key][dmod32+pad]
    __shared__ __align__(16) unsigned short Vt[2][64][40];     // [plane][d][key+pad]
    __shared__ __align__(16) unsigned short U[10240];          // Qs [2][2][64][40] / P [4][2][16][40]

    const int tid = threadIdx.x;
    const int lane = tid & 63;
    const int w = tid >> 6;
    const int mlane = lane & 15, quad = lane >> 4;
    const int colbase = h * 64;
    const int cmax = c - 1;

    // ---- stage Q tile (64 q x 64 d, row-clamped) as 2 bf16 planes ----
#pragma unroll
    for (int i = 0; i < 4; ++i) {
        int idx = tid + (i << 8);
        int r = idx >> 4, c4 = (idx & 15) << 2;
        const size_t g = (size_t)(base + min(qt * 64 + r, cmax)) * 512 + colbase + c4;
        const float4 a = *(const float4*)(Qc + g);
        float av[4] = {a.x, a.y, a.z, a.w};
        ushort4 hv, lv;
        unsigned short* hp = (unsigned short*)&hv;
        unsigned short* lp = (unsigned short*)&lv;
#pragma unroll
        for (int j = 0; j < 4; ++j) split2(av[j], hp[j], lp[j]);
        int ch = c4 >> 5, cm = c4 & 31;
        *(ushort4*)&U[(((0 * 2 + ch) * 64) + r) * 40 + cm] = hv;
        *(ushort4*)&U[(((1 * 2 + ch) * 64) + r) * 40 + cm] = lv;
    }
    __syncthreads();

    // Q B-fragments: col=q=w*16+mlane, k=d=c*32+quad*8+j (persist in regs)
    bf16_8 fq[2][2];
#pragma unroll
    for (int p = 0; p < 2; ++p)
#pragma unroll
        for (int cc = 0; cc < 2; ++cc)
            fq[p][cc] = *(const bf16_8*)&U[(((p * 2 + cc) * 64) + (w * 16 + mlane)) * 40 + quad * 8];
    __syncthreads();   // all waves done reading Qs before P region reuses U

    f32x4 oacc[4];     // O^T frags: d = mm*16+quad*4+j, q = mlane
#pragma unroll
    for (int i = 0; i < 4; ++i)
#pragma unroll
        for (int j = 0; j < 4; ++j) oacc[i][j] = 0.f;
    float m_run = -1e30f, l_run = 0.f;

    const int ta3[3] = {0, 0, 1};
    const int tb3[3] = {0, 1, 0};

    // K staging indices: 256 thr x 8 shorts = 32 keys x 64 d
    const int kr = tid >> 3, kc8 = (tid & 7) << 3;
    const int kch = kc8 >> 5, kcm = kc8 & 31;

    for (int kt = 0; kt * 32 < c; ++kt) {
        __syncthreads();
        // ---- stage K tile: pure uint4 copies from 2 planes (row-clamped) ----
        {
            const size_t g = (size_t)(base + min(kt * 32 + kr, cmax)) * 512 + colbase + kc8;
#pragma unroll
            for (int p = 0; p < 2; ++p)
                *(uint4*)&Ks[p][kch][kr][kcm] = *(const uint4*)(Kc + (size_t)p * 4194304 + g);
        }
        // ---- stage V tile transposed: 2 passes x 256 thr -> 64 d x 32 keys (row-clamped) ----
#pragma unroll
        for (int i = 0; i < 2; ++i) {
            int idx = tid + (i << 8);
            int vd = idx & 63, vk4 = (idx >> 6) << 2;
#pragma unroll
            for (int p = 0; p < 2; ++p) {
                const unsigned short* vb = Vc + (size_t)p * 4194304 + colbase + vd;
                ushort4 vv;
                vv.x = vb[(size_t)(base + min(kt * 32 + vk4 + 0, cmax)) * 512];
                vv.y = vb[(size_t)(base + min(kt * 32 + vk4 + 1, cmax)) * 512];
                vv.z = vb[(size_t)(base + min(kt * 32 + vk4 + 2, cmax)) * 512];
                vv.w = vb[(size_t)(base + min(kt * 32 + vk4 + 3, cmax)) * 512];
                *(ushort4*)&Vt[p][vd][vk4] = vv;
            }
        }
        __syncthreads();

        // ---- S^T = K·Q^T, 3-term ----
        f32x4 sacc[2];
#pragma unroll
        for (int mm = 0; mm < 2; ++mm)
#pragma unroll
            for (int j = 0; j < 4; ++j) sacc[mm][j] = 0.f;
        bf16_8 fk[2][2][2];
#pragma unroll
        for (int p = 0; p < 2; ++p)
#pragma unroll
            for (int cc = 0; cc < 2; ++cc)
#pragma unroll
                for (int mm = 0; mm < 2; ++mm)
                    fk[p][cc][mm] = *(const bf16_8*)&Ks[p][cc][mm * 16 + mlane][quad * 8];
#pragma unroll
        for (int s = 0; s < 3; ++s)
#pragma unroll
            for (int cc = 0; cc < 2; ++cc)
#pragma unroll
                for (int mm = 0; mm < 2; ++mm)
                    sacc[mm] = __builtin_amdgcn_mfma_f32_16x16x32_bf16(
                        fk[ta3[s]][cc][mm], fq[tb3[s]][cc], sacc[mm], 0, 0, 0);

        // ---- online softmax with key masking: key = kt*32 + mm*16 + quad*4 + j ----
        float sv[2][4];
#pragma unroll
        for (int mm = 0; mm < 2; ++mm)
#pragma unroll
            for (int j = 0; j < 4; ++j) {
                int kg = kt * 32 + mm * 16 + quad * 4 + j;
                sv[mm][j] = (kg < c) ? sacc[mm][j] * 0.125f : -1e30f;
            }
        float tmax = sv[0][0];
#pragma unroll
        for (int mm = 0; mm < 2; ++mm)
#pragma unroll
            for (int j = 0; j < 4; ++j) tmax = fmaxf(tmax, sv[mm][j]);
        tmax = fmaxf(tmax, __shfl_xor(tmax, 16));
        tmax = fmaxf(tmax, __shfl_xor(tmax, 32));
        float mnew = fmaxf(m_run, tmax);
        float alpha = __expf(m_run - mnew);
        float lsum = 0.f;
#pragma unroll
        for (int mm = 0; mm < 2; ++mm)
#pragma unroll
            for (int j = 0; j < 4; ++j) {
                float p = __expf(sv[mm][j] - mnew);
                sv[mm][j] = p;
                lsum += p;
            }
        lsum += __shfl_xor(lsum, 16);
        lsum += __shfl_xor(lsum, 32);
        l_run = l_run * alpha + lsum;
        m_run = mnew;
#pragma unroll
        for (int mm = 0; mm < 4; ++mm)
#pragma unroll
            for (int j = 0; j < 4; ++j) oacc[mm][j] *= alpha;

        // ---- split P to 2 bf16 planes, per-wave LDS round-trip ----
#pragma unroll
        for (int mm = 0; mm < 2; ++mm) {
            ushort4 hv, lv;
            unsigned short* hp = (unsigned short*)&hv;
            unsigned short* lp = (unsigned short*)&lv;
#pragma unroll
            for (int j = 0; j < 4; ++j) split2(sv[mm][j], hp[j], lp[j]);
            int col = mm * 16 + quad * 4;
            *(ushort4*)&U[((w * 2 + 0) * 16 + mlane) * 40 + col] = hv;
            *(ushort4*)&U[((w * 2 + 1) * 16 + mlane) * 40 + col] = lv;
        }

        // ---- O^T += V^T·P^T, 3-term ----
        bf16_8 fp[2], fv[2][4];
#pragma unroll
        for (int p = 0; p < 2; ++p) {
            fp[p] = *(const bf16_8*)&U[((w * 2 + p) * 16 + mlane) * 40 + quad * 8];
#pragma unroll
            for (int mm = 0; mm < 4; ++mm)
                fv[p][mm] = *(const bf16_8*)&Vt[p][mm * 16 + mlane][quad * 8];
        }
#pragma unroll
        for (int s = 0; s < 3; ++s)
#pragma unroll
            for (int mm = 0; mm < 4; ++mm)
                oacc[mm] = __builtin_amdgcn_mfma_f32_16x16x32_bf16(
                    fv[ta3[s]][mm], fp[tb3[s]], oacc[mm], 0, 0, 0);
    }

    // ---- zero-key correction: (1024-c) keys with logit 0, value 0 ----
    float mfin = (c < 1024) ? fmaxf(m_run, 0.f) : m_run;
    float alphaf = __expf(m_run - mfin);
    l_run = l_run * alphaf + (float)(1024 - c) * __expf(-mfin);
#pragma unroll
    for (int mm = 0; mm < 4; ++mm)
#pragma unroll
        for (int j = 0; j < 4; ++j) oacc[mm][j] *= alphaf;

    // ---- epilogue: lane holds q=w*16+mlane, d=mm*16+quad*4+j; out = attn - meanV, bf16 ----
    const int qi = w * 16 + mlane;
    if (qi < nq) {
        const float inv = 1.f / l_run;
        const size_t orow = (size_t)(base + qt * 64 + qi) * 512 + colbase;
        const float* mv = meanV + e * 65536 + b * 512 + colbase;
#pragma unroll
        for (int mm = 0; mm < 4; ++mm) {
            int d0 = mm * 16 + quad * 4;
            ushort4 o;
            o.x = f2bf(oacc[mm][0] * inv - mv[d0 + 0]);
            o.y = f2bf(oacc[mm][1] * inv - mv[d0 + 1]);
            o.z = f2bf(oacc[mm][2] * inv - mv[d0 + 2]);
            o.w = f2bf(oacc[mm][3] * inv - mv[d0 + 3]);
            *(ushort4*)&AOc[orow + d0] = o;
        }
    }
}

// ---------- meanV per (b,e,h) from 2-plane V: M32[e][b][h*64+d] = sum(h+l rows)/1024 ----------
__global__ void sumv_kernel(const unsigned short* __restrict__ Vc, const int* __restrict__ OFF,
                            float* __restrict__ M32)
{
    const int h = blockIdx.x & 7, e = (blockIdx.x >> 3) & 3, b = blockIdx.x >> 5;
    const int base = OFF[e * 8 + b], c = OFF[e * 8 + b + 1] - base;
    const int tid = threadIdx.x;
    const int d = tid & 63, g = tid >> 6;
    float s = 0.f;
    for (int r = g; r < c; r += 4) {
        const unsigned short* vp = Vc + (size_t)(base + r) * 512 + h * 64 + d;
        s += bf2f(vp[0]) + bf2f(vp[4194304]);
    }
    __shared__ float red[256];
    red[tid] = s;
    __syncthreads();
    if (g == 0)
        M32[e * 65536 + b * 512 + h * 64 + d] =
            (red[d] + red[64 + d] + red[128 + d] + red[192 + d]) * (1.f / 1024.f);
}

// ---------- embedding gather -> 3-plane bf16 split X (plane stride 8192*512) ----------
__global__ void gather_kernel(const int* __restrict__ tokens,
                              const float* __restrict__ emb,
                              unsigned short* __restrict__ Xp)
{
    const int t = blockIdx.x;
    const int tok = tokens[t];
    const int d4 = threadIdx.x * 4;
    const float4 a = *(const float4*)(emb + (size_t)tok * 512 + d4);
    float av[4] = {a.x, a.y, a.z, a.w};
    ushort4 hv, lv, l2v;
    unsigned short* hp  = (unsigned short*)&hv;
    unsigned short* lp  = (unsigned short*)&lv;
    unsigned short* l2p = (unsigned short*)&l2v;
#pragma unroll
    for (int j = 0; j < 4; ++j) split3(av[j], hp[j], lp[j], l2p[j]);
    const size_t o = (size_t)t * 512 + d4;
    *(ushort4*)&Xp[o]           = hv;
    *(ushort4*)&Xp[o + 4194304] = lv;
    *(ushort4*)&Xp[o + 8388608] = l2v;
}

// ---------- gate + argmax ----------
__global__ __launch_bounds__(256)
void gate_kernel(const float* __restrict__ H, const float* __restrict__ Wg,
                 int* __restrict__ idx)
{
    const int t = blockIdx.x * 4 + (threadIdx.x >> 6);
    const int lane = threadIdx.x & 63;
    float a0 = 0, a1 = 0, a2 = 0, a3 = 0;
#pragma unroll
    for (int i = 0; i < 8; ++i) {
        int d = i * 64 + lane;
        float hv = H[(size_t)t * 512 + d];
        a0 += hv * Wg[d * 4 + 0];
        a1 += hv * Wg[d * 4 + 1];
        a2 += hv * Wg[d * 4 + 2];
        a3 += hv * Wg[d * 4 + 3];
    }
#pragma unroll
    for (int off = 32; off > 0; off >>= 1) {
        a0 += __shfl_down(a0, off);
        a1 += __shfl_down(a1, off);
        a2 += __shfl_down(a2, off);
        a3 += __shfl_down(a3, off);
    }
    if (lane == 0) {
        int best = 0; float bv = a0;
        if (a1 > bv) { bv = a1; best = 1; }
        if (a2 > bv) { bv = a2; best = 2; }
        if (a3 > bv) { bv = a3; best = 3; }
        idx[t] = best;
    }
}

// ---------- compaction: count / offsets / fill ----------
__global__ void count_kernel(const int* __restrict__ idx, int* __restrict__ cnt)
{
    const int t = blockIdx.x * 256 + threadIdx.x;
    atomicAdd(&cnt[idx[t] * 8 + (t >> 10)], 1);
}
__global__ void offsets_kernel(const int* __restrict__ cnt, int* __restrict__ OFF,
                               int* __restrict__ cursor)
{
    if (threadIdx.x == 0) {
        int a = 0;
        for (int i = 0; i < 32; ++i) { OFF[i] = a; cursor[i] = a; a += cnt[i]; }
        OFF[32] = a;
    }
}
__global__ void fill_kernel(const int* __restrict__ idx, int* __restrict__ cursor,
                            int* __restrict__ flat)
{
    const int t = blockIdx.x * 256 + threadIdx.x;
    const int p = atomicAdd(&cursor[idx[t] * 8 + (t >> 10)], 1);
    flat[p] = t;
}

// ---------- SB[b] = sum_e G2[e][b][:] . Wout ----------
__global__ void sb_kernel(const float* __restrict__ G2, const float* __restrict__ Wout,
                          float* __restrict__ SB)
{
    const int tid = threadIdx.x;
    const int pair = tid >> 3, t8 = tid & 7;
    const int e = pair >> 3, b = pair & 7;
    float s = 0.f;
    for (int d = t8; d < 512; d += 8) s += G2[e * 65536 + b * 512 + d] * Wout[d];
    __shared__ float red[256];
    __shared__ float red2[32];
    red[tid] = s;
    __syncthreads();
    if (tid < 32) {
        float t = 0.f;
#pragma unroll
        for (int k = 0; k < 8; ++k) t += red[tid * 8 + k];
        red2[tid] = t;
    }
    __syncthreads();
    if (tid < 8)
        SB[tid] = red2[tid] + red2[8 + tid] + red2[16 + tid] + red2[24 + tid];
}

// ---------- head: out[t] = OA[t,:].Wout + SB[b(t)] ----------
__global__ __launch_bounds__(256)
void wout_kernel(const float* __restrict__ OUT, const float* __restrict__ Wout,
                 const float* __restrict__ SB, float* __restrict__ out)
{
    const int t = blockIdx.x * 4 + (threadIdx.x >> 6);
    const int lane = threadIdx.x & 63;
    float s = 0.f;
#pragma unroll
    for (int i = 0; i < 8; ++i) {
        int d = i * 64 + lane;
        s += OUT[(size_t)t * 512 + d] * Wout[d];
    }
#pragma unroll
    for (int off = 32; off > 0; off >>= 1) s += __shfl_down(s, off);
    if (lane == 0) out[t] = s + SB[t >> 10];
}

// ---------- launch ----------
extern "C" void kernel_launch(void* const* d_in, const int* in_sizes, int n_in,
                              void* d_out, int out_size, void* d_ws, size_t ws_size,
                              hipStream_t stream)
{
    const int*   tokens = (const int*)d_in[0];
    const float* emb  = (const float*)d_in[1];
    const float* Wq   = (const float*)d_in[2];
    const float* Wk   = (const float*)d_in[3];
    const float* Wv   = (const float*)d_in[4];
    const float* Wo   = (const float*)d_in[5];
    const float* W1   = (const float*)d_in[6];
    const float* W2   = (const float*)d_in[7];
    const float* Wg   = (const float*)d_in[8];
    const float* eWq  = (const float*)d_in[9];
    const float* eWk  = (const float*)d_in[10];
    const float* eWv  = (const float*)d_in[11];
    const float* eWo  = (const float*)d_in[12];
    const float* eW1  = (const float*)d_in[13];
    const float* eW2  = (const float*)d_in[14];
    const float* Wout = (const float*)d_in[15];
    float* outp = (float*)d_out;

    float* WS = (float*)d_ws;
    const size_t SZ = (size_t)8192 * 512;
    float* P0 = WS, *P1 = WS + SZ, *P2 = WS + 2 * SZ, *P3 = WS + 3 * SZ, *P4 = WS + 4 * SZ;

    // weight planes (shorts) after the 5 f32 planes
    unsigned short* SP   = (unsigned short*)(WS + 5 * SZ);
    unsigned short* sW1p = SP;                      // [3][2048][512]
    unsigned short* sW2p = SP + 3145728;            // [3][512][2048]
    unsigned short* xWq  = SP + 6291456;            // shared: [3][512][512] -> later expert [4][512][512]
    unsigned short* xWk  = xWq + 1048576;
    unsigned short* xWv  = xWk + 1048576;
    unsigned short* xWo  = xWv + 1048576;
    unsigned short* xW1  = xWo + 1048576;           // [4][2048][512]
    unsigned short* xW2  = xW1 + 4194304;           // [4][512][2048]

    float* MBase = WS + 5 * SZ + 9437184;           // misc region
    int* IDX    = (int*)MBase;
    int* cnt    = (int*)(MBase + 8192);
    int* OFFp   = (int*)(MBase + 8224);
    int* cursor = (int*)(MBase + 8264);
    int* flat   = (int*)(MBase + 8304);
    float* M32  = MBase + 16640;                    // [4][128][512]
    float* G0   = M32 + 262144;
    float* G2   = G0 + 262144;
    float* SB   = G2 + 262144;

    // shared-phase aliases
    float* Qb = P0, *AO = P3, *T0 = P4, *T1 = P0, *Hb = P4;
    unsigned short* Xp  = (unsigned short*)P3;            // [3][8192][512] bf16 @48-72MB; dead after QKV
    unsigned short* Kpp = (unsigned short*)P1;            // K 3-plane, stride 4194304 sh (16-40MB)
    unsigned short* Vpp = (unsigned short*)(WS + 10485760); // V 3-plane, stride 16777216 sh:
                                                          // 8MB payloads @40-48, 72-80, 104-112MB
                                                          // (plane2 overlays xW1/xW2 -> expert wsplits deferred)
    // expert-phase aliases
    float* Qc = P0;
    unsigned short* KcP = (unsigned short*)P1;            // K 2-plane compact, stride 4194304 sh
    unsigned short* VcP = (unsigned short*)P2;            // V 2-plane compact, stride 4194304 sh
    unsigned short* AOc = (unsigned short*)P3;            // [8192][512] bf16 (P3a)
    unsigned short* T0c = (unsigned short*)(P3 + 2097152);// [8192][512] bf16 (P3b)
    unsigned short* T1c = (unsigned short*)P0;            // [8192][2048] bf16 (P0..P1)
    float* G1 = P2;                                       // [4][128][2048] (written after attn_compact)
    float* OA = P3;

    const int M = 8192, D = 512, FF = 2048;
    const size_t sDD = (size_t)D * D, sDF = (size_t)D * FF;
    const float* NUL = nullptr;
    float* NULm = nullptr;

    // ---- weight prep: shared FFN + shared QKV/O (3-plane). Expert wsplits deferred
    //      (their regions are time-shared with Vpp plane2). ----
    wsplit_kernel<3><<<dim3(32, 8, 1),  256, 0, stream>>>(W1, NUL, NUL, NUL, sW1p, 0, 0, 0, D, FF, 1, 0, 0);
    wsplit_kernel<3><<<dim3(8, 32, 1),  256, 0, stream>>>(W2, NUL, NUL, NUL, sW2p, 0, 0, 0, FF, D, 1, 0, 0);
    wsplit_kernel<3><<<dim3(8, 8, 4),   256, 0, stream>>>(Wq, Wk, Wv, Wo, xWq, xWk, xWv, xWo, D, D, 1, 0, 0);

    // ---- shared block (argmax-safe, 6-term; A pre-split, K/V emitted as 3-plane bf16) ----
    gather_kernel<<<8192, 128, 0, stream>>>(tokens, emb, Xp);
    gemm_kernel<6, 0, 0, 1, 1, 1, 0><<<dim3(64, 4, 1), 256, 0, stream>>>(
        Xp, xWq, NUL, NUL, Qb, NULm, NULm, M, D, D, (size_t)M * D, 0, 0, nullptr, nullptr);
    gemm_kernel<6, 0, 0, 1, 1, 1, 2><<<dim3(64, 4, 1), 256, 0, stream>>>(
        Xp, xWk, NUL, NUL, Kpp, NULm, NULm, M, D, D, (size_t)M * D, 0, 4194304, nullptr, nullptr);
    gemm_kernel<6, 0, 0, 1, 1, 1, 2><<<dim3(64, 4, 1), 256, 0, stream>>>(
        Xp, xWv, NUL, NUL, Vpp, NULm, NULm, M, D, D, (size_t)M * D, 0, 16777216, nullptr, nullptr);
    attn_kernel<<<1024, 256, 0, stream>>>(Qb, Kpp, Vpp, AO);
    gemm_kernel<6, 0, 0, 1, 1, 0, 0><<<dim3(64, 4, 1), 256, 0, stream>>>(
        AO, xWo, NUL, NUL, T0, NULm, NULm, M, D, D, 0, 0, 0, nullptr, nullptr);
    // shared Wq..Wo planes + Vpp now dead -> expert weight splits
    wsplit_kernel<1><<<dim3(8, 8, 16),  256, 0, stream>>>(eWq, eWk, eWv, eWo, xWq, xWk, xWv, xWo, D, D, 4, sDD, 262144);
    wsplit_kernel<1><<<dim3(32, 8, 4),  256, 0, stream>>>(eW1, NUL, NUL, NUL, xW1, 0, 0, 0, D, FF, 4, sDF, 1048576);
    wsplit_kernel<1><<<dim3(8, 32, 4),  256, 0, stream>>>(eW2, NUL, NUL, NUL, xW2, 0, 0, 0, FF, D, 4, sDF, 1048576);
    gemm_kernel<6, 0, 0, 1, 1, 0, 0><<<dim3(64, 16, 1), 256, 0, stream>>>(
        T0, sW1p, NUL, NUL, T1, NULm, NULm, M, FF, D, 0, 0, 0, nullptr, nullptr);
    gemm_kernel<6, 0, 0, 1, 1, 0, 0><<<dim3(64, 4, 1), 256, 0, stream>>>(
        T1, sW2p, NUL, NUL, Hb, NULm, NULm, M, D, FF, 0, 0, 0, nullptr, nullptr);
    gate_kernel<<<2048, 256, 0, stream>>>(Hb, Wg, IDX);

    // ---- compaction ----
    hipMemsetAsync(cnt, 0, 32 * sizeof(int), stream);
    hipMemsetAsync(M32, 0, 4 * 128 * 512 * sizeof(float), stream);
    hipMemsetAsync(G2, 0, 262144 * sizeof(float), stream);   // meanV stage-3 accumulates
    count_kernel<<<32, 256, 0, stream>>>(IDX, cnt);
    offsets_kernel<<<1, 64, 0, stream>>>(cnt, OFFp, cursor);
    fill_kernel<<<32, 256, 0, stream>>>(IDX, cursor, flat);

    // ---- expert QKV (gather A=Hb f32; Q f32, K/V emitted as 2-plane bf16 compact) ----
    gemm_kernel<1, 2, 1, 1, 1, 0, 0><<<dim3(64, 4, 4), 256, 0, stream>>>(
        Hb, xWq, NUL, NUL, Qc, NULm, NULm, M, D, D, 0, 262144, 0, OFFp, flat);
    gemm_kernel<1, 2, 1, 1, 1, 0, 3><<<dim3(64, 4, 4), 256, 0, stream>>>(
        Hb, xWk, NUL, NUL, KcP, NULm, NULm, M, D, D, 0, 262144, 4194304, OFFp, flat);
    gemm_kernel<1, 2, 1, 1, 1, 0, 3><<<dim3(64, 4, 4), 256, 0, stream>>>(
        Hb, xWv, NUL, NUL, VcP, NULm, NULm, M, D, D, 0, 262144, 4194304, OFFp, flat);
    sumv_kernel<<<256, 256, 0, stream>>>(VcP, OFFp, M32);
    attn_compact_kernel<<<4096, 256, 0, stream>>>(Qc, KcP, VcP, M32, AOc, OFFp);

    // ---- expert FFN chain (A bf16 direct, B planes, C bf16) ----
    gemm_kernel<1, 1, 1, 1, 1, 1, 1><<<dim3(64, 4, 4), 256, 0, stream>>>(
        AOc, xWo, NUL, NUL, T0c, NULm, NULm, M, D, D, 0, 262144, 0, OFFp, flat);
    gemm_kernel<1, 1, 1, 1, 1, 1, 1><<<dim3(64, 16, 4), 256, 0, stream>>>(
        T0c, xW1, NUL, NUL, T1c, NULm, NULm, M, FF, D, 0, 1048576, 0, OFFp, flat);

    // ---- meanV path: dedicated tiny-M kernels (weights read once, coalesced) ----
    meanv_gemm_kernel<<<dim3(8, 1, 4),  256, 0, stream>>>(M32, eWo, G0, 512,  512,  65536,  sDD, 65536);
    meanv_gemm_kernel<<<dim3(32, 1, 4), 256, 0, stream>>>(G0,  eW1, G1, 2048, 512,  65536,  sDF, 262144);
    meanv_gemm_kernel<<<dim3(8, 4, 4),  256, 0, stream>>>(G1,  eW2, G2, 512,  2048, 262144, sDF, 65536);

    // ---- expert W2: A=T1c bf16, scatter f32 into OA ----
    gemm_kernel<1, 1, 2, 1, 1, 1, 0><<<dim3(64, 4, 4), 256, 0, stream>>>(
        T1c, xW2, NUL, NUL, OA, NULm, NULm, M, D, FF, 0, 1048576, 0, OFFp, flat);

    sb_kernel<<<1, 256, 0, stream>>>(G2, Wout, SB);
    wout_kernel<<<2048, 256, 0, stream>>>(OA, Wout, SB, outp);
}